// Round 1
// baseline (486.271 us; speedup 1.0000x reference)
//
#include <hip/hip_runtime.h>
#include <math.h>

// ---------------------------------------------------------------------------
// ComprehensiveGANLoss: scalar = feature_matching + musical + adversarial
// Shapes: B=32, S=2048, P=128, D=512
// Dominant cost: 4 big fp32 tensors (real/fake local/input) = 512 MiB read.
// Memory-bound; target ~90-120us.
// ---------------------------------------------------------------------------

#define B_ 32
#define S_ 2048
#define P_ 128
#define D_ 512

__global__ void zero_out_kernel(float* out) {
    if (threadIdx.x == 0 && blockIdx.x == 0) out[0] = 0.0f;
}

// One wave (64 lanes) per position-task.
// task 0..2047        : local,  s = task
// task 2048..4095     : input,  s = task-2048
// task 4096..4223     : phrase, p = task-4096
// task 4224           : global
// Each task: for 32 rows of real (sign -1) and 32 rows of fake (sign +1),
// L2-normalize the 512-float row (wave butterfly reduce of sum-of-squares),
// accumulate sgn * x * inv_norm into per-lane acc[8]. Then sum(acc^2) over
// the wave and atomicAdd(scale * sum).
__global__ __launch_bounds__(256) void fm_kernel(
    const float* __restrict__ real_local, const float* __restrict__ real_phrase,
    const float* __restrict__ real_global, const float* __restrict__ real_input,
    const float* __restrict__ fake_local, const float* __restrict__ fake_phrase,
    const float* __restrict__ fake_global, const float* __restrict__ fake_input,
    float* __restrict__ out)
{
    const int NTASK = 2 * S_ + P_ + 1;  // 4225
    int gtid = blockIdx.x * blockDim.x + threadIdx.x;
    int wave_id = gtid >> 6;
    int lane = threadIdx.x & 63;
    if (wave_id >= NTASK) return;

    const float* rp;
    const float* fp;
    long long base;
    long long rowStride;
    float scale;

    if (wave_id < S_) {
        int s = wave_id;
        rp = real_local; fp = fake_local;
        base = (long long)s * D_;
        rowStride = (long long)S_ * D_;
        // w/4 * (1/32)^2 * 1/(S*D)
        scale = 0.4f / (4.0f * 1024.0f * (float)S_ * (float)D_);
    } else if (wave_id < 2 * S_) {
        int s = wave_id - S_;
        rp = real_input; fp = fake_input;
        base = (long long)s * D_;
        rowStride = (long long)S_ * D_;
        scale = 0.1f / (4.0f * 1024.0f * (float)S_ * (float)D_);
    } else if (wave_id < 2 * S_ + P_) {
        int p = wave_id - 2 * S_;
        rp = real_phrase; fp = fake_phrase;
        base = (long long)p * D_;
        rowStride = (long long)P_ * D_;
        scale = 0.4f / (4.0f * 1024.0f * (float)P_ * (float)D_);
    } else {
        rp = real_global; fp = fake_global;
        base = 0;
        rowStride = D_;
        scale = 0.2f / (4.0f * 1024.0f * (float)D_);
    }

    // lane d-coverage: [4*lane, 4*lane+4) and [256+4*lane, 256+4*lane+4)
    float4 a0 = {0.f, 0.f, 0.f, 0.f};
    float4 a1 = {0.f, 0.f, 0.f, 0.f};

    #pragma unroll 1
    for (int pass = 0; pass < 2; ++pass) {
        const float* ptr = pass ? fp : rp;
        const float sgn = pass ? 1.0f : -1.0f;
        #pragma unroll 1
        for (int b = 0; b < B_; ++b) {
            const float4* row = (const float4*)(ptr + base + (long long)b * rowStride);
            float4 x0 = row[lane];
            float4 x1 = row[64 + lane];
            float ss = x0.x * x0.x + x0.y * x0.y + x0.z * x0.z + x0.w * x0.w
                     + x1.x * x1.x + x1.y * x1.y + x1.z * x1.z + x1.w * x1.w;
            // butterfly: all lanes end with full sum
            #pragma unroll
            for (int off = 32; off > 0; off >>= 1)
                ss += __shfl_xor(ss, off, 64);
            float inv = sgn / fmaxf(sqrtf(ss), 1e-12f);
            a0.x = fmaf(x0.x, inv, a0.x);
            a0.y = fmaf(x0.y, inv, a0.y);
            a0.z = fmaf(x0.z, inv, a0.z);
            a0.w = fmaf(x0.w, inv, a0.w);
            a1.x = fmaf(x1.x, inv, a1.x);
            a1.y = fmaf(x1.y, inv, a1.y);
            a1.z = fmaf(x1.z, inv, a1.z);
            a1.w = fmaf(x1.w, inv, a1.w);
        }
    }

    float ssum = a0.x * a0.x + a0.y * a0.y + a0.z * a0.z + a0.w * a0.w
               + a1.x * a1.x + a1.y * a1.y + a1.z * a1.z + a1.w * a1.w;
    #pragma unroll
    for (int off = 32; off > 0; off >>= 1)
        ssum += __shfl_xor(ssum, off, 64);

    if (lane == 0) atomicAdd(out, ssum * scale);
}

__device__ __forceinline__ float softplus_neg(float x) {
    // softplus(-x) = max(-x,0) + log1p(exp(-| -x |))
    float z = -x;
    return fmaxf(z, 0.0f) + log1pf(expf(-fabsf(z)));
}

// Musical-perceptual (tokens) + adversarial (logits). 65536 threads total.
__global__ __launch_bounds__(256) void small_kernel(
    const float* __restrict__ local_logits,
    const float* __restrict__ phrase_logits,
    const float* __restrict__ global_logits,
    const int* __restrict__ tokens,
    float* __restrict__ out)
{
    int gid = blockIdx.x * blockDim.x + threadIdx.x;
    float acc = 0.0f;

    // --- musical: one thread per (b, j) pair, j in [0, S-1) ---
    const int NPAIR = B_ * (S_ - 1);  // 65504
    if (gid < NPAIR) {
        int b = gid / (S_ - 1);
        int j = gid - b * (S_ - 1);
        int t0 = tokens[b * S_ + j];
        int t1 = tokens[b * S_ + j + 1];
        float ts0 = (t0 >= 256 && t0 < 768) ? 1.0f : 0.0f;
        float ts1 = (t1 >= 256 && t1 < 768) ? 1.0f : 0.0f;
        float rhythm = fabsf(ts1 - ts0);
        int p0 = (t0 < 128) ? t0 : 0;
        int p1 = (t1 < 128) ? t1 : 0;
        int pc0 = p0 % 12;
        int pc1 = p1 % 12;
        int iv = abs(pc0 - pc1);
        float harsh = (iv == 6 || iv == 11) ? 1.0f : 0.0f;
        int pd = p1 - p0;
        float mel = (abs(pd) > 12) ? 1.0f : 0.0f;
        acc += rhythm * (1.0f / (float)NPAIR)
             + harsh * (1.0f / ((float)B_ * (float)S_))
             + mel * (1.0f / (float)NPAIR);
    }

    // --- adversarial ---
    if (gid < B_ * S_)   acc += 0.4f * softplus_neg(local_logits[gid])  / (float)(B_ * S_);
    if (gid < B_ * P_)   acc += 0.4f * softplus_neg(phrase_logits[gid]) / (float)(B_ * P_);
    if (gid < B_)        acc += 0.2f * softplus_neg(global_logits[gid]) / (float)B_;

    // block reduce: wave butterfly then LDS across 4 waves
    #pragma unroll
    for (int off = 32; off > 0; off >>= 1)
        acc += __shfl_xor(acc, off, 64);

    __shared__ float warp_sums[4];
    int wid = threadIdx.x >> 6;
    int lane = threadIdx.x & 63;
    if (lane == 0) warp_sums[wid] = acc;
    __syncthreads();
    if (threadIdx.x == 0) {
        float t = warp_sums[0] + warp_sums[1] + warp_sums[2] + warp_sums[3];
        atomicAdd(out, t);
    }
}

extern "C" void kernel_launch(void* const* d_in, const int* in_sizes, int n_in,
                              void* d_out, int out_size, void* d_ws, size_t ws_size,
                              hipStream_t stream) {
    const float* real_local   = (const float*)d_in[0];
    const float* real_phrase  = (const float*)d_in[1];
    const float* real_global  = (const float*)d_in[2];
    const float* real_input   = (const float*)d_in[3];
    const float* fake_local   = (const float*)d_in[4];
    const float* fake_phrase  = (const float*)d_in[5];
    const float* fake_global  = (const float*)d_in[6];
    const float* fake_input   = (const float*)d_in[7];
    const float* local_logits  = (const float*)d_in[8];
    const float* phrase_logits = (const float*)d_in[9];
    const float* global_logits = (const float*)d_in[10];
    const int*   tokens        = (const int*)d_in[11];
    float* out = (float*)d_out;

    zero_out_kernel<<<1, 64, 0, stream>>>(out);

    const int NTASK = 2 * S_ + P_ + 1;              // 4225 waves
    int fm_blocks = (NTASK * 64 + 255) / 256;       // 1057 blocks of 4 waves
    fm_kernel<<<fm_blocks, 256, 0, stream>>>(
        real_local, real_phrase, real_global, real_input,
        fake_local, fake_phrase, fake_global, fake_input, out);

    small_kernel<<<(B_ * S_) / 256, 256, 0, stream>>>(
        local_logits, phrase_logits, global_logits, tokens, out);
}

// Round 2
// 465.892 us; speedup vs baseline: 1.0437x; 1.0437x over previous
//
#include <hip/hip_runtime.h>
#include <math.h>

// ---------------------------------------------------------------------------
// ComprehensiveGANLoss: scalar = feature_matching + musical + adversarial
// B=32, S=2048, P=128, D=512. Memory-bound: 553 MB read once.
//
// fm_kernel: one BLOCK per "position task" (2048 local + 2048 input +
// 128 phrase + 1 global = 4225 tasks). Each task = 64 rows (32 real, 32 fake)
// of 512 floats. Within a block: 4 waves × (16 lanes/row × 4 rows/iter),
// 8 float4 loads in flight per iteration (vs 2 in R1), 4-step shuffle reduce
// for the row norm (vs 6), partials combined in LDS, one atomicAdd per block.
// ---------------------------------------------------------------------------

#define B_ 32
#define S_ 2048
#define P_ 128
#define D_ 512
#define NTASK (2 * S_ + P_ + 1)  // 4225

__global__ void zero_out_kernel(float* out) {
    if (threadIdx.x == 0 && blockIdx.x == 0) out[0] = 0.0f;
}

__global__ __launch_bounds__(256) void fm_kernel(
    const float* __restrict__ real_local, const float* __restrict__ real_phrase,
    const float* __restrict__ real_global, const float* __restrict__ real_input,
    const float* __restrict__ fake_local, const float* __restrict__ fake_phrase,
    const float* __restrict__ fake_global, const float* __restrict__ fake_input,
    float* __restrict__ out)
{
    const int task = blockIdx.x;           // one task per block
    const int part = threadIdx.x >> 6;     // wave in block, 0..3
    const int lane = threadIdx.x & 63;
    const int r = lane >> 4;               // row-in-group, 0..3
    const int c = lane & 15;               // 16 lanes cover one 512-float row

    const float* rp; const float* fp;
    long long base, rowStride;
    float scale;
    if (task < S_) {
        rp = real_local; fp = fake_local;
        base = (long long)task * D_; rowStride = (long long)S_ * D_;
        scale = 0.4f / (4.0f * 1024.0f * (float)S_ * (float)D_);
    } else if (task < 2 * S_) {
        int s = task - S_;
        rp = real_input; fp = fake_input;
        base = (long long)s * D_; rowStride = (long long)S_ * D_;
        scale = 0.1f / (4.0f * 1024.0f * (float)S_ * (float)D_);
    } else if (task < 2 * S_ + P_) {
        int p = task - 2 * S_;
        rp = real_phrase; fp = fake_phrase;
        base = (long long)p * D_; rowStride = (long long)P_ * D_;
        scale = 0.4f / (4.0f * 1024.0f * (float)P_ * (float)D_);
    } else {
        rp = real_global; fp = fake_global;
        base = 0; rowStride = D_;
        scale = 0.2f / (4.0f * 1024.0f * (float)D_);
    }

    // acc[j]: partial sum over this wave's rows of sgn*x/||row|| at
    // d = 4*c + 64*j + comp  (replicated across the 4 r-groups after reduce)
    float4 acc[8];
    #pragma unroll
    for (int j = 0; j < 8; ++j) acc[j] = make_float4(0.f, 0.f, 0.f, 0.f);

    // 16 row-groups of 4 rows; this wave handles groups part*4 .. part*4+3
    #pragma unroll 1
    for (int gi = 0; gi < 4; ++gi) {
        int g = part * 4 + gi;
        int combo = g * 4 + r;             // 0..63: 0..31 real, 32..63 fake
        int pass = combo >> 5;
        int b = combo & 31;
        const float4* row4 = (const float4*)((pass ? fp : rp) + base
                              + (long long)b * rowStride);
        float4 x[8];
        #pragma unroll
        for (int j = 0; j < 8; ++j) x[j] = row4[c + 16 * j];  // 8 loads in flight

        float ss = 0.f;
        #pragma unroll
        for (int j = 0; j < 8; ++j)
            ss += x[j].x * x[j].x + x[j].y * x[j].y
                + x[j].z * x[j].z + x[j].w * x[j].w;
        // reduce across the 16 lanes of this row (4 steps, intra-32 swizzles)
        ss += __shfl_xor(ss, 1, 64);
        ss += __shfl_xor(ss, 2, 64);
        ss += __shfl_xor(ss, 4, 64);
        ss += __shfl_xor(ss, 8, 64);

        float inv = (pass ? 1.0f : -1.0f) / fmaxf(sqrtf(ss), 1e-12f);
        #pragma unroll
        for (int j = 0; j < 8; ++j) {
            acc[j].x = fmaf(x[j].x, inv, acc[j].x);
            acc[j].y = fmaf(x[j].y, inv, acc[j].y);
            acc[j].z = fmaf(x[j].z, inv, acc[j].z);
            acc[j].w = fmaf(x[j].w, inv, acc[j].w);
        }
    }

    // combine across the 4 r-groups (butterfly xor 16, 32)
    #pragma unroll
    for (int j = 0; j < 8; ++j) {
        acc[j].x += __shfl_xor(acc[j].x, 16, 64);
        acc[j].y += __shfl_xor(acc[j].y, 16, 64);
        acc[j].z += __shfl_xor(acc[j].z, 16, 64);
        acc[j].w += __shfl_xor(acc[j].w, 16, 64);
        acc[j].x += __shfl_xor(acc[j].x, 32, 64);
        acc[j].y += __shfl_xor(acc[j].y, 32, 64);
        acc[j].z += __shfl_xor(acc[j].z, 32, 64);
        acc[j].w += __shfl_xor(acc[j].w, 32, 64);
    }

    // per-wave 512-float partial vector -> LDS  (float4 index 16*j + c)
    __shared__ float part_vec[4 * 512];
    __shared__ float wave_sums[4];
    float4* pv = (float4*)(part_vec + part * 512);
    if (r == 0) {
        pv[c]      = acc[0];
        pv[16 + c] = acc[1];
        pv[32 + c] = acc[2];
        pv[48 + c] = acc[3];
    } else if (r == 1) {
        pv[64 + c]  = acc[4];
        pv[80 + c]  = acc[5];
        pv[96 + c]  = acc[6];
        pv[112 + c] = acc[7];
    }
    __syncthreads();

    // sum the 4 partials and square: each thread owns 2 d-positions
    const float2* pv2 = (const float2*)part_vec;
    int tid = threadIdx.x;
    float2 a0 = pv2[tid];
    float2 a1 = pv2[256 + tid];
    float2 a2 = pv2[512 + tid];
    float2 a3 = pv2[768 + tid];
    float v0 = a0.x + a1.x + a2.x + a3.x;
    float v1 = a0.y + a1.y + a2.y + a3.y;
    float ssq = v0 * v0 + v1 * v1;

    #pragma unroll
    for (int off = 32; off > 0; off >>= 1)
        ssq += __shfl_xor(ssq, off, 64);
    if (lane == 0) wave_sums[part] = ssq;
    __syncthreads();
    if (tid == 0) {
        float t = wave_sums[0] + wave_sums[1] + wave_sums[2] + wave_sums[3];
        atomicAdd(out, t * scale);
    }
}

__device__ __forceinline__ float softplus_neg(float x) {
    float z = -x;
    return fmaxf(z, 0.0f) + log1pf(expf(-fabsf(z)));
}

__global__ __launch_bounds__(256) void small_kernel(
    const float* __restrict__ local_logits,
    const float* __restrict__ phrase_logits,
    const float* __restrict__ global_logits,
    const int* __restrict__ tokens,
    float* __restrict__ out)
{
    int gid = blockIdx.x * blockDim.x + threadIdx.x;
    float acc = 0.0f;

    const int NPAIR = B_ * (S_ - 1);  // 65504
    if (gid < NPAIR) {
        int b = gid / (S_ - 1);
        int j = gid - b * (S_ - 1);
        int t0 = tokens[b * S_ + j];
        int t1 = tokens[b * S_ + j + 1];
        float ts0 = (t0 >= 256 && t0 < 768) ? 1.0f : 0.0f;
        float ts1 = (t1 >= 256 && t1 < 768) ? 1.0f : 0.0f;
        float rhythm = fabsf(ts1 - ts0);
        int p0 = (t0 < 128) ? t0 : 0;
        int p1 = (t1 < 128) ? t1 : 0;
        int iv = abs(p0 % 12 - p1 % 12);
        float harsh = (iv == 6 || iv == 11) ? 1.0f : 0.0f;
        float mel = (abs(p1 - p0) > 12) ? 1.0f : 0.0f;
        acc += rhythm * (1.0f / (float)NPAIR)
             + harsh * (1.0f / ((float)B_ * (float)S_))
             + mel * (1.0f / (float)NPAIR);
    }

    if (gid < B_ * S_)   acc += 0.4f * softplus_neg(local_logits[gid])  / (float)(B_ * S_);
    if (gid < B_ * P_)   acc += 0.4f * softplus_neg(phrase_logits[gid]) / (float)(B_ * P_);
    if (gid < B_)        acc += 0.2f * softplus_neg(global_logits[gid]) / (float)B_;

    #pragma unroll
    for (int off = 32; off > 0; off >>= 1)
        acc += __shfl_xor(acc, off, 64);

    __shared__ float warp_sums[4];
    int wid = threadIdx.x >> 6;
    int lane = threadIdx.x & 63;
    if (lane == 0) warp_sums[wid] = acc;
    __syncthreads();
    if (threadIdx.x == 0) {
        float t = warp_sums[0] + warp_sums[1] + warp_sums[2] + warp_sums[3];
        atomicAdd(out, t);
    }
}

extern "C" void kernel_launch(void* const* d_in, const int* in_sizes, int n_in,
                              void* d_out, int out_size, void* d_ws, size_t ws_size,
                              hipStream_t stream) {
    const float* real_local   = (const float*)d_in[0];
    const float* real_phrase  = (const float*)d_in[1];
    const float* real_global  = (const float*)d_in[2];
    const float* real_input   = (const float*)d_in[3];
    const float* fake_local   = (const float*)d_in[4];
    const float* fake_phrase  = (const float*)d_in[5];
    const float* fake_global  = (const float*)d_in[6];
    const float* fake_input   = (const float*)d_in[7];
    const float* local_logits  = (const float*)d_in[8];
    const float* phrase_logits = (const float*)d_in[9];
    const float* global_logits = (const float*)d_in[10];
    const int*   tokens        = (const int*)d_in[11];
    float* out = (float*)d_out;

    zero_out_kernel<<<1, 64, 0, stream>>>(out);

    fm_kernel<<<NTASK, 256, 0, stream>>>(
        real_local, real_phrase, real_global, real_input,
        fake_local, fake_phrase, fake_global, fake_input, out);

    small_kernel<<<(B_ * S_) / 256, 256, 0, stream>>>(
        local_logits, phrase_logits, global_logits, tokens, out);
}

// Round 3
// 465.549 us; speedup vs baseline: 1.0445x; 1.0007x over previous
//
#include <hip/hip_runtime.h>
#include <math.h>

// ---------------------------------------------------------------------------
// ComprehensiveGANLoss: scalar = feature_matching + musical + adversarial
// B=32, S=2048, P=128, D=512. Memory-bound: 553 MB read once.
//
// R3: contiguous-streaming fm kernel. R1/R2 read 2-KB columns at 4-MiB
// power-of-two stride (64 aliasing streams per task) and plateaued at
// ~3.3 TB/s effective. Now: one block per 4-consecutive-s tile; each wave
// owns one full row (2 KB contiguous) and loops over b, loading real+fake
// rows as whole-wave contiguous loads. Concurrent blocks sweep the same
// b-plane at adjacent addresses -> near-linear HBM sweep.
// Per-thread register acc (8 floats) = sum_b(+-x_hat) for fixed (s, d-slice);
// square-reduce + one atomicAdd per block. No workspace.
// ---------------------------------------------------------------------------

#define B_ 32
#define S_ 2048
#define P_ 128
#define D_ 512

#define TILE_S 4
#define NT_LOCAL  (S_ / TILE_S)              // 512
#define NT_INPUT  (S_ / TILE_S)              // 512
#define NT_PHRASE (P_ / TILE_S)              // 32
#define NTASK (NT_LOCAL + NT_INPUT + NT_PHRASE + 1)  // 1057

__global__ void zero_out_kernel(float* out) {
    if (threadIdx.x == 0 && blockIdx.x == 0) out[0] = 0.0f;
}

__device__ __forceinline__ float sum8(float4 a, float4 b) {
    return a.x * a.x + a.y * a.y + a.z * a.z + a.w * a.w
         + b.x * b.x + b.y * b.y + b.z * b.z + b.w * b.w;
}

__global__ __launch_bounds__(256) void fm_stream(
    const float* __restrict__ real_local, const float* __restrict__ real_phrase,
    const float* __restrict__ real_global, const float* __restrict__ real_input,
    const float* __restrict__ fake_local, const float* __restrict__ fake_phrase,
    const float* __restrict__ fake_global, const float* __restrict__ fake_input,
    float* __restrict__ out)
{
    const int task = blockIdx.x;
    const int w = threadIdx.x >> 6;       // wave id = row-in-tile (s offset)
    const int c = threadIdx.x & 63;       // lane: covers d=4c..4c+3 and 256+4c..

    const float* rp; const float* fp;
    long long rowBase;                    // float offset of this wave's row
    long long rs4;                        // float4 stride between b-rows
    float scale;
    bool active = true;

    if (task < NT_LOCAL) {
        rp = real_local; fp = fake_local;
        rowBase = (long long)(task * TILE_S + w) * D_;
        rs4 = (long long)S_ * D_ / 4;
        scale = 0.4f / (4.0f * 1024.0f * (float)S_ * (float)D_);
    } else if (task < NT_LOCAL + NT_INPUT) {
        int t = task - NT_LOCAL;
        rp = real_input; fp = fake_input;
        rowBase = (long long)(t * TILE_S + w) * D_;
        rs4 = (long long)S_ * D_ / 4;
        scale = 0.1f / (4.0f * 1024.0f * (float)S_ * (float)D_);
    } else if (task < NT_LOCAL + NT_INPUT + NT_PHRASE) {
        int t = task - NT_LOCAL - NT_INPUT;
        rp = real_phrase; fp = fake_phrase;
        rowBase = (long long)(t * TILE_S + w) * D_;
        rs4 = (long long)P_ * D_ / 4;
        scale = 0.4f / (4.0f * 1024.0f * (float)P_ * (float)D_);
    } else {
        rp = real_global; fp = fake_global;
        rowBase = 0;
        rs4 = D_ / 4;
        scale = 0.2f / (4.0f * 1024.0f * (float)D_);
        active = (w == 0);                // (B, D): a single "row" task
    }

    float4 a0 = make_float4(0.f, 0.f, 0.f, 0.f);
    float4 a1 = make_float4(0.f, 0.f, 0.f, 0.f);

    if (active) {
        const float4* r4 = (const float4*)(rp + rowBase);
        const float4* f4 = (const float4*)(fp + rowBase);
        #pragma unroll 2
        for (int b = 0; b < B_; ++b) {
            const float4* rb = r4 + (long long)b * rs4;   // scalar base
            const float4* fb = f4 + (long long)b * rs4;
            float4 x0 = rb[c];
            float4 x1 = rb[64 + c];
            float4 y0 = fb[c];
            float4 y1 = fb[64 + c];

            float ssr = sum8(x0, x1);
            float ssf = sum8(y0, y1);
            #pragma unroll
            for (int off = 1; off <= 32; off <<= 1) {
                ssr += __shfl_xor(ssr, off, 64);
                ssf += __shfl_xor(ssf, off, 64);
            }
            float ir = -1.0f / fmaxf(sqrtf(ssr), 1e-12f);
            float jf =  1.0f / fmaxf(sqrtf(ssf), 1e-12f);

            a0.x = fmaf(x0.x, ir, fmaf(y0.x, jf, a0.x));
            a0.y = fmaf(x0.y, ir, fmaf(y0.y, jf, a0.y));
            a0.z = fmaf(x0.z, ir, fmaf(y0.z, jf, a0.z));
            a0.w = fmaf(x0.w, ir, fmaf(y0.w, jf, a0.w));
            a1.x = fmaf(x1.x, ir, fmaf(y1.x, jf, a1.x));
            a1.y = fmaf(x1.y, ir, fmaf(y1.y, jf, a1.y));
            a1.z = fmaf(x1.z, ir, fmaf(y1.z, jf, a1.z));
            a1.w = fmaf(x1.w, ir, fmaf(y1.w, jf, a1.w));
        }
    }

    float ssq = sum8(a0, a1);
    #pragma unroll
    for (int off = 1; off <= 32; off <<= 1)
        ssq += __shfl_xor(ssq, off, 64);

    __shared__ float wave_sums[4];
    if (c == 0) wave_sums[w] = ssq;
    __syncthreads();
    if (threadIdx.x == 0) {
        float t = wave_sums[0] + wave_sums[1] + wave_sums[2] + wave_sums[3];
        atomicAdd(out, t * scale);
    }
}

__device__ __forceinline__ float softplus_neg(float x) {
    float z = -x;
    return fmaxf(z, 0.0f) + log1pf(expf(-fabsf(z)));
}

__global__ __launch_bounds__(256) void small_kernel(
    const float* __restrict__ local_logits,
    const float* __restrict__ phrase_logits,
    const float* __restrict__ global_logits,
    const int* __restrict__ tokens,
    float* __restrict__ out)
{
    int gid = blockIdx.x * blockDim.x + threadIdx.x;
    float acc = 0.0f;

    const int NPAIR = B_ * (S_ - 1);  // 65504
    if (gid < NPAIR) {
        int b = gid / (S_ - 1);
        int j = gid - b * (S_ - 1);
        int t0 = tokens[b * S_ + j];
        int t1 = tokens[b * S_ + j + 1];
        float ts0 = (t0 >= 256 && t0 < 768) ? 1.0f : 0.0f;
        float ts1 = (t1 >= 256 && t1 < 768) ? 1.0f : 0.0f;
        float rhythm = fabsf(ts1 - ts0);
        int p0 = (t0 < 128) ? t0 : 0;
        int p1 = (t1 < 128) ? t1 : 0;
        int iv = abs(p0 % 12 - p1 % 12);
        float harsh = (iv == 6 || iv == 11) ? 1.0f : 0.0f;
        float mel = (abs(p1 - p0) > 12) ? 1.0f : 0.0f;
        acc += rhythm * (1.0f / (float)NPAIR)
             + harsh * (1.0f / ((float)B_ * (float)S_))
             + mel * (1.0f / (float)NPAIR);
    }

    if (gid < B_ * S_)   acc += 0.4f * softplus_neg(local_logits[gid])  / (float)(B_ * S_);
    if (gid < B_ * P_)   acc += 0.4f * softplus_neg(phrase_logits[gid]) / (float)(B_ * P_);
    if (gid < B_)        acc += 0.2f * softplus_neg(global_logits[gid]) / (float)B_;

    #pragma unroll
    for (int off = 32; off > 0; off >>= 1)
        acc += __shfl_xor(acc, off, 64);

    __shared__ float warp_sums[4];
    int wid = threadIdx.x >> 6;
    int lane = threadIdx.x & 63;
    if (lane == 0) warp_sums[wid] = acc;
    __syncthreads();
    if (threadIdx.x == 0) {
        float t = warp_sums[0] + warp_sums[1] + warp_sums[2] + warp_sums[3];
        atomicAdd(out, t);
    }
}

extern "C" void kernel_launch(void* const* d_in, const int* in_sizes, int n_in,
                              void* d_out, int out_size, void* d_ws, size_t ws_size,
                              hipStream_t stream) {
    const float* real_local   = (const float*)d_in[0];
    const float* real_phrase  = (const float*)d_in[1];
    const float* real_global  = (const float*)d_in[2];
    const float* real_input   = (const float*)d_in[3];
    const float* fake_local   = (const float*)d_in[4];
    const float* fake_phrase  = (const float*)d_in[5];
    const float* fake_global  = (const float*)d_in[6];
    const float* fake_input   = (const float*)d_in[7];
    const float* local_logits  = (const float*)d_in[8];
    const float* phrase_logits = (const float*)d_in[9];
    const float* global_logits = (const float*)d_in[10];
    const int*   tokens        = (const int*)d_in[11];
    float* out = (float*)d_out;

    zero_out_kernel<<<1, 64, 0, stream>>>(out);

    fm_stream<<<NTASK, 256, 0, stream>>>(
        real_local, real_phrase, real_global, real_input,
        fake_local, fake_phrase, fake_global, fake_input, out);

    small_kernel<<<(B_ * S_) / 256, 256, 0, stream>>>(
        local_logits, phrase_logits, global_logits, tokens, out);
}